// Round 9
// baseline (344.323 us; speedup 1.0000x reference)
//
#include <hip/hip_runtime.h>
#include <stdint.h>

typedef float  f32x4  __attribute__((ext_vector_type(4)));
typedef __bf16 bf16x8 __attribute__((ext_vector_type(8)));

#define AS1 __attribute__((address_space(1)))
#define AS3 __attribute__((address_space(3)))

// Problem constants: B=2, S=2048, HID=2048, NH=16, HD=128, RING=4, CH=512, DIL=2
// packed length per (b,h,parity) = 1024; packed kv-chunk = 256
// BLOCKED operand layout (both GEMMs): elem(r, k) at
//   ((k>>5)*RB + (r>>7))*4096 + ((k>>3)&3)*1024 + (r&127)*8 + (k&7)
// where RB = number of 128-row blocks. LDS staging is then an identity copy.

// ---- convert x -> BLOCKED bf16 A for GEMM1 (RB=32) ----
__global__ void k_cvt_x_blk(const float* __restrict__ x, __bf16* __restrict__ y) {
  const int d = blockIdx.x * 256 + threadIdx.x;
  const int row = d & 127, kg = (d >> 7) & 3, mbkt = d >> 9;
  const int mb = mbkt & 31, kt = mbkt >> 5;
  const int m = mb * 128 + row, k0 = kt * 32 + kg * 8;
  const float4 v0 = *reinterpret_cast<const float4*>(x + (size_t)m * 2048 + k0);
  const float4 v1 = *reinterpret_cast<const float4*>(x + (size_t)m * 2048 + k0 + 4);
  bf16x8 o;
  o[0] = (__bf16)v0.x; o[1] = (__bf16)v0.y; o[2] = (__bf16)v0.z; o[3] = (__bf16)v0.w;
  o[4] = (__bf16)v1.x; o[5] = (__bf16)v1.y; o[6] = (__bf16)v1.z; o[7] = (__bf16)v1.w;
  *reinterpret_cast<bf16x8*>(y + (size_t)d * 8) = o;
}

// ------- transpose+convert W[K][N] f32 -> BLOCKED bf16 B (RB = NBK) -------
__global__ void k_cvt_wt_blk(const float* __restrict__ w, __bf16* __restrict__ wt,
                             const int N, const int NBK) {
  __shared__ float tile[64][65];
  const int k0 = blockIdx.x * 64, n0 = blockIdx.y * 64;
  const int t = threadIdx.x;
  #pragma unroll
  for (int i = 0; i < 16; ++i) {
    const int idx = t + 256 * i;
    const int r = idx >> 6, c = idx & 63;   // r = k-off, c = n-off
    tile[r][c] = w[(size_t)(k0 + r) * N + n0 + c];
  }
  __syncthreads();
  #pragma unroll
  for (int i = 0; i < 16; ++i) {
    const int idx = t + 256 * i;
    const int nn = idx >> 6, kk = idx & 63;  // kk fastest -> contiguous runs
    const int n = n0 + nn, k = k0 + kk;
    const size_t dst = ((size_t)(k >> 5) * NBK + (n >> 7)) * 4096 +
                       (size_t)((k >> 3) & 3) * 1024 + (n & 127) * 8 + (k & 7);
    wt[dst] = (__bf16)tile[kk][nn];
  }
}

// ---------------- unified pipelined blocked GEMM: C = A * B^T ----------------
// BM=128, BN=256, BK=32, 4 waves (wq: 64-row half, wc: 128-col half); per-wave
// output 64x128 -> acc[4][8] (128 AGPR; 32 MFMA per 12 ds_read_b128 per K-step:
// matrix-pipe-limited, fixes round-8's LDS-read-bound 4x4 shape).
// Triple-buffered LDS (72KB, 2 blocks/CU), prefetch distance 2, steady-state
// s_waitcnt vmcnt(6) (never 0), raw s_barrier, setprio; NO sched_barrier (m141).
// XCD-chunked: XCD x owns nb in [x*NBX, x*NBX+NBX) (B strip L2-resident),
// streams all 32 mb (A L3-resident after first XCD pass).
// EPI 1: scatter into parity-packed Q,K (s-major) + V (d-major).
// EPI 2: f32 row-major out (N=2048).
template<int NBB, int NBX, int EPI>
__global__ __launch_bounds__(256, 2) void k_gemm_blk(
    const __bf16* __restrict__ Ab, const __bf16* __restrict__ Bb,
    __bf16* __restrict__ Oq, __bf16* __restrict__ Ok, __bf16* __restrict__ Ov,
    float* __restrict__ Of) {
  __shared__ __bf16 As[3][4096];
  __shared__ __bf16 Bs[3][8192];
  const int tid = threadIdx.x;
  const int w = tid >> 6, l = tid & 63, g = l >> 4, l15 = l & 15;
  const int wq = w >> 1, wc = w & 1;
  const int bx = blockIdx.x;
  const int xcd = bx & 7, win = bx >> 3;
  const int nb = xcd * NBX + win / 32;     // 256-col n-block
  const int mb = win % 32;                 // 128-row m-block

  f32x4 acc[4][8] = {};

  auto STAGE = [&](int t, int b) {
    const __bf16* abase = Ab + ((size_t)t * 32 + mb) * 4096;
    #pragma unroll
    for (int i = 0; i < 2; ++i) {
      const int ch = w * 2 + i;
      __builtin_amdgcn_global_load_lds((const AS1 uint32_t*)(abase + ch * 512 + l * 8),
                                       (AS3 uint32_t*)(&As[b][ch * 512]), 16, 0, 0);
    }
    const __bf16* bbase = Bb + ((size_t)t * NBB + nb * 2) * 4096;
    #pragma unroll
    for (int i = 0; i < 4; ++i) {
      const int cb = w * 4 + i;
      __builtin_amdgcn_global_load_lds((const AS1 uint32_t*)(bbase + cb * 512 + l * 8),
                                       (AS3 uint32_t*)(&Bs[b][cb * 512]), 16, 0, 0);
    }
  };

  STAGE(0, 0);
  STAGE(1, 1);
  asm volatile("s_waitcnt vmcnt(6)" ::: "memory");   // tile 0 landed, tile 1 flying
  __builtin_amdgcn_s_barrier();

  int cur = 0;
  for (int t = 0; t < 64; ++t) {
    int b2 = cur + 2; if (b2 >= 3) b2 -= 3;
    if (t + 2 < 64) STAGE(t + 2, b2);
    bf16x8 af[4], bfr[8];
    #pragma unroll
    for (int mi = 0; mi < 4; ++mi)
      af[mi] = *reinterpret_cast<const bf16x8*>(
          &As[cur][g * 1024 + (wq * 64 + mi * 16 + l15) * 8]);
    #pragma unroll
    for (int ni = 0; ni < 8; ++ni)
      bfr[ni] = *reinterpret_cast<const bf16x8*>(
          &Bs[cur][wc * 4096 + g * 1024 + (ni * 16 + l15) * 8]);
    __builtin_amdgcn_s_setprio(1);
    #pragma unroll
    for (int mi = 0; mi < 4; ++mi)
      #pragma unroll
      for (int ni = 0; ni < 8; ++ni)
        acc[mi][ni] = __builtin_amdgcn_mfma_f32_16x16x32_bf16(af[mi], bfr[ni], acc[mi][ni], 0, 0, 0);
    __builtin_amdgcn_s_setprio(0);
    if (t < 62) asm volatile("s_waitcnt vmcnt(6)" ::: "memory");  // retire tile t+1
    else        asm volatile("s_waitcnt vmcnt(0)" ::: "memory");  // tail drain
    __builtin_amdgcn_s_barrier();
    cur = cur + 1; if (cur >= 3) cur -= 3;
  }

  if constexpr (EPI == 1) {
    const int n0 = nb * 256 + wc * 128;
    const int ty = n0 >> 11;               // 0:q 1:k 2:v
    const int h = (n0 & 2047) >> 7;
    #pragma unroll
    for (int mi = 0; mi < 4; ++mi) {
      #pragma unroll
      for (int r = 0; r < 4; ++r) {
        const int m = mb * 128 + wq * 64 + mi * 16 + 4 * g + r;
        const int s = m & 2047;
        const int sp = s & 1, s2 = s >> 1;
        const int bb = m >> 11;
        const size_t base = ((((size_t)bb * 16 + h) * 2 + sp) << 17);
        #pragma unroll
        for (int ni = 0; ni < 8; ++ni) {
          const int d = ni * 16 + l15;
          const __bf16 v = (__bf16)acc[mi][ni][r];
          if (ty == 0)      Oq[base + (size_t)s2 * 128 + d] = v;
          else if (ty == 1) Ok[base + (size_t)s2 * 128 + d] = v;
          else              Ov[base + (size_t)d * 1024 + s2] = v;
        }
      }
    }
  } else {
    #pragma unroll
    for (int mi = 0; mi < 4; ++mi)
      #pragma unroll
      for (int r = 0; r < 4; ++r) {
        const int m = mb * 128 + wq * 64 + mi * 16 + 4 * g + r;
        #pragma unroll
        for (int ni = 0; ni < 8; ++ni) {
          const int n = nb * 256 + wc * 128 + ni * 16 + l15;
          Of[(size_t)m * 2048 + n] = acc[mi][ni][r];
        }
      }
  }
}

// ---------------- fused dilated ring attention v4 ----------------
// (round-7-proven; epilogue now writes BLOCKED A layout for GEMM2)
__global__ __launch_bounds__(256, 2) void k_attn(
    const __bf16* __restrict__ Qp, const __bf16* __restrict__ Kp,
    const __bf16* __restrict__ Vt, __bf16* __restrict__ attnA) {
  __shared__ __bf16 Ks[64 * 128];
  __shared__ __bf16 Vs[128 * 64];
  __shared__ __bf16 E[4][16][136];

  const int bx = blockIdx.x;
  const int wid = (bx & 7) * 128 + (bx >> 3);
  const int qt = wid & 15, p = (wid >> 4) & 1, h = (wid >> 5) & 15, b = wid >> 9;
  const int tid = threadIdx.x;
  const int w = tid >> 6, l = tid & 63, g = l >> 4, l15 = l & 15;
  const size_t base = ((((size_t)b * 16 + h) * 2 + p) << 17);
  const __bf16* Qb = Qp + base;
  const __bf16* Kb = Kp + base;
  const __bf16* Vb = Vt + base;
  const int q0 = qt * 64 + w * 16;
  const float SC = 1.4426950408889634f / 11.313708498984761f;

  bf16x8 qf[4];
  #pragma unroll
  for (int ks = 0; ks < 4; ++ks)
    qf[ks] = *reinterpret_cast<const bf16x8*>(Qb + (size_t)(q0 + l15) * 128 + ks * 32 + 8 * g);

  f32x4 num[8] = {};
  float den[4] = {0.f, 0.f, 0.f, 0.f};

  const int krow_in = l >> 4;
  const int vrow_in = l >> 3;
  const int vsrc_e = (((l & 7) * 16) ^ (vrow_in << 4)) >> 1;

  for (int c = 0; c < 4; ++c) {
    f32x4 s[16] = {};
    #pragma unroll
    for (int st = 0; st < 4; ++st) {
      __syncthreads();
      #pragma unroll
      for (int i = 0; i < 4; ++i) {
        const int ch = w * 4 + i;
        const int row = ch * 4 + krow_in;
        const int cb = (l15 * 16) ^ ((row & 7) << 4);
        const __bf16* src = Kb + (size_t)(c * 256 + st * 64 + row) * 128 + (cb >> 1);
        __builtin_amdgcn_global_load_lds((const AS1 uint32_t*)src,
                                         (AS3 uint32_t*)(Ks + ch * 512), 16, 0, 0);
      }
      __syncthreads();
      #pragma unroll
      for (int ks = 0; ks < 4; ++ks) {
        #pragma unroll
        for (int nf2 = 0; nf2 < 4; ++nf2) {
          const int r = nf2 * 16 + l15;
          const int cb = (ks * 64 + g * 16) ^ ((r & 7) << 4);
          const bf16x8 kf = *reinterpret_cast<const bf16x8*>(Ks + r * 128 + (cb >> 1));
          s[st * 4 + nf2] = __builtin_amdgcn_mfma_f32_16x16x32_bf16(qf[ks], kf, s[st * 4 + nf2], 0, 0, 0);
        }
      }
    }
    float mv[4];
    #pragma unroll
    for (int r = 0; r < 4; ++r) {
      float m0v = s[0][r];
      #pragma unroll
      for (int nf = 1; nf < 16; ++nf) m0v = fmaxf(m0v, s[nf][r]);
      m0v = fmaxf(m0v, __shfl_xor(m0v, 1));
      m0v = fmaxf(m0v, __shfl_xor(m0v, 2));
      m0v = fmaxf(m0v, __shfl_xor(m0v, 4));
      m0v = fmaxf(m0v, __shfl_xor(m0v, 8));
      mv[r] = m0v;
    }
    #pragma unroll
    for (int r = 0; r < 4; ++r) {
      float ds = 0.f;
      #pragma unroll
      for (int nf = 0; nf < 16; ++nf) {
        const float e = exp2f((s[nf][r] - mv[r]) * SC);
        s[nf][r] = e;
        ds += e;
      }
      den[r] += ds;
    }
    #pragma unroll
    for (int h2 = 0; h2 < 2; ++h2) {
      #pragma unroll
      for (int nf = 0; nf < 8; ++nf)
        #pragma unroll
        for (int r = 0; r < 4; ++r)
          E[w][4 * g + r][nf * 16 + l15] = (__bf16)s[h2 * 8 + nf][r];
      #pragma unroll
      for (int sv = 0; sv < 2; ++sv) {
        const int kv0 = c * 256 + h2 * 128 + sv * 64;
        __syncthreads();
        #pragma unroll
        for (int i = 0; i < 4; ++i) {
          const int ch = w * 4 + i;
          const int row = ch * 8 + vrow_in;
          const __bf16* src = Vb + (size_t)row * 1024 + kv0 + vsrc_e;
          __builtin_amdgcn_global_load_lds((const AS1 uint32_t*)src,
                                           (AS3 uint32_t*)(Vs + ch * 512), 16, 0, 0);
        }
        __syncthreads();
        #pragma unroll
        for (int ks2 = 0; ks2 < 2; ++ks2) {
          const bf16x8 a = *reinterpret_cast<const bf16x8*>(
              &E[w][l15][sv * 64 + ks2 * 32 + 8 * g]);
          #pragma unroll
          for (int nd = 0; nd < 8; ++nd) {
            const int d = nd * 16 + l15;
            const int cb = (ks2 * 64 + g * 16) ^ ((d & 7) << 4);
            const bf16x8 vf = *reinterpret_cast<const bf16x8*>(Vs + d * 64 + (cb >> 1));
            num[nd] = __builtin_amdgcn_mfma_f32_16x16x32_bf16(a, vf, num[nd], 0, 0, 0);
          }
        }
      }
    }
  }

  #pragma unroll
  for (int r = 0; r < 4; ++r) {
    den[r] += __shfl_xor(den[r], 1);
    den[r] += __shfl_xor(den[r], 2);
    den[r] += __shfl_xor(den[r], 4);
    den[r] += __shfl_xor(den[r], 8);
    den[r] += 1e-8f;
  }

  // epilogue: write BLOCKED A (RB=32) for GEMM2: m = b*2048+srow, k = h*128+d
  #pragma unroll
  for (int nd = 0; nd < 8; ++nd)
    #pragma unroll
    for (int r = 0; r < 4; ++r) {
      const int sq = q0 + 4 * g + r;
      const int srow = 2 * sq + p;
      const int m = b * 2048 + srow;
      const int k = h * 128 + nd * 16 + l15;
      const size_t dst = ((size_t)(k >> 5) * 32 + (m >> 7)) * 4096 +
                         (size_t)((k >> 3) & 3) * 1024 + (m & 127) * 8 + (k & 7);
      attnA[dst] = (__bf16)(num[nd][r] / den[r]);
    }
}

extern "C" void kernel_launch(void* const* d_in, const int* in_sizes, int n_in,
                              void* d_out, int out_size, void* d_ws, size_t ws_size,
                              hipStream_t stream) {
  (void)in_sizes; (void)n_in; (void)out_size; (void)ws_size;
  const float* x    = (const float*)d_in[0];
  const float* wqkv = (const float*)d_in[1];
  const float* wout = (const float*)d_in[2];
  float* out = (float*)d_out;
  uint8_t* ws = (uint8_t*)d_ws;

  // workspace layout (bytes); total needed = 96 MB
  __bf16* xbf   = (__bf16*)(ws + 0);                    // 16 MB blocked A (GEMM1)
  __bf16* wqkvt = (__bf16*)(ws + (16ull << 20));        // 24 MB blocked B (GEMM1, RB=48)
  __bf16* woutt = (__bf16*)(ws + (40ull << 20));        //  8 MB blocked B (GEMM2, RB=16)
  __bf16* Qp    = (__bf16*)(ws + (48ull << 20));        // 16 MB [b][h][p][1024][128]
  __bf16* Kp    = (__bf16*)(ws + (64ull << 20));        // 16 MB [b][h][p][1024][128]
  __bf16* Vt    = (__bf16*)(ws + (80ull << 20));        // 16 MB [b][h][p][128][1024]
  __bf16* attnA = (__bf16*)(ws + 0);                    // 16 MB blocked A (GEMM2); reuse xbf

  k_cvt_x_blk<<<4096, 256, 0, stream>>>(x, xbf);
  k_cvt_wt_blk<<<dim3(32, 96), 256, 0, stream>>>(wqkv, wqkvt, 6144, 48);
  k_cvt_wt_blk<<<dim3(32, 32), 256, 0, stream>>>(wout, woutt, 2048, 16);
  // qkv projection (pipelined blocked, 24 nb: 3 per XCD), fused parity-pack+V^T
  k_gemm_blk<48, 3, 1><<<768, 256, 0, stream>>>(xbf, wqkvt, Qp, Kp, Vt, nullptr);
  // fused dilated attention (writes blocked A for GEMM2)
  k_attn<<<1024, 256, 0, stream>>>(Qp, Kp, Vt, attnA);
  // output projection (pipelined blocked, 8 nb: 1 per XCD) -> f32
  k_gemm_blk<16, 1, 2><<<256, 256, 0, stream>>>(attnA, woutt, nullptr, nullptr, nullptr, out);
}

// Round 12
// 300.650 us; speedup vs baseline: 1.1453x; 1.1453x over previous
//
#include <hip/hip_runtime.h>
#include <stdint.h>

typedef float  f32x4  __attribute__((ext_vector_type(4)));
typedef __bf16 bf16x8 __attribute__((ext_vector_type(8)));

#define AS1 __attribute__((address_space(1)))
#define AS3 __attribute__((address_space(3)))

// Problem constants: B=2, S=2048, HID=2048, NH=16, HD=128, RING=4, CH=512, DIL=2
// packed length per (b,h,parity) = 1024; packed kv-chunk = 256
// BLOCKED operand layout (both GEMMs): elem(r, k) at
//   ((k>>5)*RB + (r>>7))*4096 + ((k>>3)&3)*1024 + (r&127)*8 + (k&7)
// RB = number of 128-row blocks. LDS staging is an identity copy.

// ---- convert x -> BLOCKED bf16 A for GEMM1 (RB=32) ----
__global__ void k_cvt_x_blk(const float* __restrict__ x, __bf16* __restrict__ y) {
  const int d = blockIdx.x * 256 + threadIdx.x;
  const int row = d & 127, kg = (d >> 7) & 3, mbkt = d >> 9;
  const int mb = mbkt & 31, kt = mbkt >> 5;
  const int m = mb * 128 + row, k0 = kt * 32 + kg * 8;
  const float4 v0 = *reinterpret_cast<const float4*>(x + (size_t)m * 2048 + k0);
  const float4 v1 = *reinterpret_cast<const float4*>(x + (size_t)m * 2048 + k0 + 4);
  bf16x8 o;
  o[0] = (__bf16)v0.x; o[1] = (__bf16)v0.y; o[2] = (__bf16)v0.z; o[3] = (__bf16)v0.w;
  o[4] = (__bf16)v1.x; o[5] = (__bf16)v1.y; o[6] = (__bf16)v1.z; o[7] = (__bf16)v1.w;
  *reinterpret_cast<bf16x8*>(y + (size_t)d * 8) = o;
}

// ------- transpose+convert W[K][N] f32 -> BLOCKED bf16 B (RB = NBK) -------
__global__ void k_cvt_wt_blk(const float* __restrict__ w, __bf16* __restrict__ wt,
                             const int N, const int NBK) {
  __shared__ float tile[64][65];
  const int k0 = blockIdx.x * 64, n0 = blockIdx.y * 64;
  const int t = threadIdx.x;
  #pragma unroll
  for (int i = 0; i < 16; ++i) {
    const int idx = t + 256 * i;
    const int r = idx >> 6, c = idx & 63;
    tile[r][c] = w[(size_t)(k0 + r) * N + n0 + c];
  }
  __syncthreads();
  #pragma unroll
  for (int i = 0; i < 16; ++i) {
    const int idx = t + 256 * i;
    const int nn = idx >> 6, kk = idx & 63;
    const int n = n0 + nn, k = k0 + kk;
    const size_t dst = ((size_t)(k >> 5) * NBK + (n >> 7)) * 4096 +
                       (size_t)((k >> 3) & 3) * 1024 + (n & 127) * 8 + (k & 7);
    wt[dst] = (__bf16)tile[kk][nn];
  }
}

// ---------------- pipelined blocked GEMM v8: C = A * B^T ----------------
// ROUND-8-PROVEN sync structure, unchanged: triple-buffered LDS, prefetch
// distance 2, same-iteration fragment consumption (compiler's lgkmcnt before
// MFMA guarantees reads complete before the barrier -> no WAR race), counted
// vmcnt(4) (retires exactly tile t+1's 4 loads/wave), builtin s_barrier.
// v7's cross-iteration register pipeline (reads crossing the barrier) NaN'd
// twice -> abandoned.
// Fixed vs round 8 (index-level only):
//  - XCD nb-strip mapping: nb = xcd*NBX + win%NBX, mb = win/NBX. B strip
//    (NBX*128 cols x K x 2B <= 3MB) stays L2-resident; A streams via L3.
//    (round 8's mapping streamed ALL of B per XCD -> FETCH 205MB)
//  - template also serves GEMM2 at grid 512 = 2 blocks/CU (round 9 ran 1/CU).
template<int NBB, int NBX, int EPI>
__global__ __launch_bounds__(256, 2) void k_gemm_v8(
    const __bf16* __restrict__ Ab, const __bf16* __restrict__ Bb,
    __bf16* __restrict__ Oq, __bf16* __restrict__ Ok, __bf16* __restrict__ Ov,
    float* __restrict__ Of) {
  __shared__ __bf16 As[3][4096];
  __shared__ __bf16 Bs[3][4096];
  const int tid = threadIdx.x;
  const int w = tid >> 6, l = tid & 63, g = l >> 4, l15 = l & 15;
  const int wr = w >> 1, wc = w & 1;
  const int bx = blockIdx.x;
  const int xcd = bx & 7, win = bx >> 3;
  const int nb = xcd * NBX + win % NBX;    // 128-col n-block (strip per XCD)
  const int mb = win / NBX;                // 128-row m-block

  f32x4 acc[4][4] = {};

  auto STAGE = [&](int t, int b) {
    const __bf16* ap = Ab + ((size_t)t * 32 + mb) * 4096 + w * 1024 + l * 8;
    const __bf16* bp = Bb + ((size_t)t * NBB + nb) * 4096 + w * 1024 + l * 8;
    __builtin_amdgcn_global_load_lds((const AS1 uint32_t*)ap,
                                     (AS3 uint32_t*)(&As[b][w * 1024]), 16, 0, 0);
    __builtin_amdgcn_global_load_lds((const AS1 uint32_t*)(ap + 512),
                                     (AS3 uint32_t*)(&As[b][w * 1024 + 512]), 16, 0, 0);
    __builtin_amdgcn_global_load_lds((const AS1 uint32_t*)bp,
                                     (AS3 uint32_t*)(&Bs[b][w * 1024]), 16, 0, 0);
    __builtin_amdgcn_global_load_lds((const AS1 uint32_t*)(bp + 512),
                                     (AS3 uint32_t*)(&Bs[b][w * 1024 + 512]), 16, 0, 0);
  };

  // prologue: tiles 0,1 in flight; retire tile 0 (keep tile 1 flying)
  STAGE(0, 0);
  STAGE(1, 1);
  asm volatile("s_waitcnt vmcnt(4)" ::: "memory");
  __builtin_amdgcn_s_barrier();

  int cur = 0;
  for (int t = 0; t < 64; ++t) {
    int b2 = cur + 2; if (b2 >= 3) b2 -= 3;
    if (t + 2 < 64) STAGE(t + 2, b2);
    bf16x8 af[4], bfr[4];
    #pragma unroll
    for (int mi = 0; mi < 4; ++mi)
      af[mi] = *reinterpret_cast<const bf16x8*>(
          &As[cur][g * 1024 + (wr * 64 + mi * 16 + l15) * 8]);
    #pragma unroll
    for (int ni = 0; ni < 4; ++ni)
      bfr[ni] = *reinterpret_cast<const bf16x8*>(
          &Bs[cur][g * 1024 + (wc * 64 + ni * 16 + l15) * 8]);
    __builtin_amdgcn_s_setprio(1);
    #pragma unroll
    for (int mi = 0; mi < 4; ++mi)
      #pragma unroll
      for (int ni = 0; ni < 4; ++ni)
        acc[mi][ni] = __builtin_amdgcn_mfma_f32_16x16x32_bf16(af[mi], bfr[ni], acc[mi][ni], 0, 0, 0);
    __builtin_amdgcn_s_setprio(0);
    if (t < 62) asm volatile("s_waitcnt vmcnt(4)" ::: "memory");  // retire tile t+1
    else        asm volatile("s_waitcnt vmcnt(0)" ::: "memory");  // tail drain
    __builtin_amdgcn_s_barrier();
    cur = cur + 1; if (cur >= 3) cur -= 3;
  }

  if constexpr (EPI == 1) {
    const int n0 = nb * 128;
    const int ty = n0 >> 11;               // 0:q 1:k 2:v
    const int h = (n0 & 2047) >> 7;
    #pragma unroll
    for (int mi = 0; mi < 4; ++mi) {
      #pragma unroll
      for (int r = 0; r < 4; ++r) {
        const int m = mb * 128 + wr * 64 + mi * 16 + 4 * g + r;
        const int s = m & 2047;
        const int sp = s & 1, s2 = s >> 1;
        const int bb = m >> 11;
        const size_t base = ((((size_t)bb * 16 + h) * 2 + sp) << 17);
        #pragma unroll
        for (int ni = 0; ni < 4; ++ni) {
          const int d = wc * 64 + ni * 16 + l15;
          const __bf16 v = (__bf16)acc[mi][ni][r];
          if (ty == 0)      Oq[base + (size_t)s2 * 128 + d] = v;
          else if (ty == 1) Ok[base + (size_t)s2 * 128 + d] = v;
          else              Ov[base + (size_t)d * 1024 + s2] = v;
        }
      }
    }
  } else {
    #pragma unroll
    for (int mi = 0; mi < 4; ++mi)
      #pragma unroll
      for (int r = 0; r < 4; ++r) {
        const int m = mb * 128 + wr * 64 + mi * 16 + 4 * g + r;
        #pragma unroll
        for (int ni = 0; ni < 4; ++ni) {
          const int n = nb * 128 + wc * 64 + ni * 16 + l15;
          Of[(size_t)m * 2048 + n] = acc[mi][ni][r];
        }
      }
  }
}

// ---------------- fused dilated ring attention v4 (round-9 proven) ----------------
__global__ __launch_bounds__(256, 2) void k_attn(
    const __bf16* __restrict__ Qp, const __bf16* __restrict__ Kp,
    const __bf16* __restrict__ Vt, __bf16* __restrict__ attnA) {
  __shared__ __bf16 Ks[64 * 128];
  __shared__ __bf16 Vs[128 * 64];
  __shared__ __bf16 E[4][16][136];

  const int bx = blockIdx.x;
  const int wid = (bx & 7) * 128 + (bx >> 3);
  const int qt = wid & 15, p = (wid >> 4) & 1, h = (wid >> 5) & 15, b = wid >> 9;
  const int tid = threadIdx.x;
  const int w = tid >> 6, l = tid & 63, g = l >> 4, l15 = l & 15;
  const size_t base = ((((size_t)b * 16 + h) * 2 + p) << 17);
  const __bf16* Qb = Qp + base;
  const __bf16* Kb = Kp + base;
  const __bf16* Vb = Vt + base;
  const int q0 = qt * 64 + w * 16;
  const float SC = 1.4426950408889634f / 11.313708498984761f;

  bf16x8 qf[4];
  #pragma unroll
  for (int ks = 0; ks < 4; ++ks)
    qf[ks] = *reinterpret_cast<const bf16x8*>(Qb + (size_t)(q0 + l15) * 128 + ks * 32 + 8 * g);

  f32x4 num[8] = {};
  float den[4] = {0.f, 0.f, 0.f, 0.f};

  const int krow_in = l >> 4;
  const int vrow_in = l >> 3;
  const int vsrc_e = (((l & 7) * 16) ^ (vrow_in << 4)) >> 1;

  for (int c = 0; c < 4; ++c) {
    f32x4 s[16] = {};
    #pragma unroll
    for (int st = 0; st < 4; ++st) {
      __syncthreads();
      #pragma unroll
      for (int i = 0; i < 4; ++i) {
        const int ch = w * 4 + i;
        const int row = ch * 4 + krow_in;
        const int cb = (l15 * 16) ^ ((row & 7) << 4);
        const __bf16* src = Kb + (size_t)(c * 256 + st * 64 + row) * 128 + (cb >> 1);
        __builtin_amdgcn_global_load_lds((const AS1 uint32_t*)src,
                                         (AS3 uint32_t*)(Ks + ch * 512), 16, 0, 0);
      }
      __syncthreads();
      #pragma unroll
      for (int ks = 0; ks < 4; ++ks) {
        #pragma unroll
        for (int nf2 = 0; nf2 < 4; ++nf2) {
          const int r = nf2 * 16 + l15;
          const int cb = (ks * 64 + g * 16) ^ ((r & 7) << 4);
          const bf16x8 kf = *reinterpret_cast<const bf16x8*>(Ks + r * 128 + (cb >> 1));
          s[st * 4 + nf2] = __builtin_amdgcn_mfma_f32_16x16x32_bf16(qf[ks], kf, s[st * 4 + nf2], 0, 0, 0);
        }
      }
    }
    float mv[4];
    #pragma unroll
    for (int r = 0; r < 4; ++r) {
      float m0v = s[0][r];
      #pragma unroll
      for (int nf = 1; nf < 16; ++nf) m0v = fmaxf(m0v, s[nf][r]);
      m0v = fmaxf(m0v, __shfl_xor(m0v, 1));
      m0v = fmaxf(m0v, __shfl_xor(m0v, 2));
      m0v = fmaxf(m0v, __shfl_xor(m0v, 4));
      m0v = fmaxf(m0v, __shfl_xor(m0v, 8));
      mv[r] = m0v;
    }
    #pragma unroll
    for (int r = 0; r < 4; ++r) {
      float ds = 0.f;
      #pragma unroll
      for (int nf = 0; nf < 16; ++nf) {
        const float e = exp2f((s[nf][r] - mv[r]) * SC);
        s[nf][r] = e;
        ds += e;
      }
      den[r] += ds;
    }
    #pragma unroll
    for (int h2 = 0; h2 < 2; ++h2) {
      #pragma unroll
      for (int nf = 0; nf < 8; ++nf)
        #pragma unroll
        for (int r = 0; r < 4; ++r)
          E[w][4 * g + r][nf * 16 + l15] = (__bf16)s[h2 * 8 + nf][r];
      #pragma unroll
      for (int sv = 0; sv < 2; ++sv) {
        const int kv0 = c * 256 + h2 * 128 + sv * 64;
        __syncthreads();
        #pragma unroll
        for (int i = 0; i < 4; ++i) {
          const int ch = w * 4 + i;
          const int row = ch * 8 + vrow_in;
          const __bf16* src = Vb + (size_t)row * 1024 + kv0 + vsrc_e;
          __builtin_amdgcn_global_load_lds((const AS1 uint32_t*)src,
                                           (AS3 uint32_t*)(Vs + ch * 512), 16, 0, 0);
        }
        __syncthreads();
        #pragma unroll
        for (int ks2 = 0; ks2 < 2; ++ks2) {
          const bf16x8 a = *reinterpret_cast<const bf16x8*>(
              &E[w][l15][sv * 64 + ks2 * 32 + 8 * g]);
          #pragma unroll
          for (int nd = 0; nd < 8; ++nd) {
            const int d = nd * 16 + l15;
            const int cb = (ks2 * 64 + g * 16) ^ ((d & 7) << 4);
            const bf16x8 vf = *reinterpret_cast<const bf16x8*>(Vs + d * 64 + (cb >> 1));
            num[nd] = __builtin_amdgcn_mfma_f32_16x16x32_bf16(a, vf, num[nd], 0, 0, 0);
          }
        }
      }
    }
  }

  #pragma unroll
  for (int r = 0; r < 4; ++r) {
    den[r] += __shfl_xor(den[r], 1);
    den[r] += __shfl_xor(den[r], 2);
    den[r] += __shfl_xor(den[r], 4);
    den[r] += __shfl_xor(den[r], 8);
    den[r] += 1e-8f;
  }

  // epilogue: write BLOCKED A (RB=32) for GEMM2: m = b*2048+srow, k = h*128+d
  #pragma unroll
  for (int nd = 0; nd < 8; ++nd)
    #pragma unroll
    for (int r = 0; r < 4; ++r) {
      const int sq = q0 + 4 * g + r;
      const int srow = 2 * sq + p;
      const int m = b * 2048 + srow;
      const int k = h * 128 + nd * 16 + l15;
      const size_t dst = ((size_t)(k >> 5) * 32 + (m >> 7)) * 4096 +
                         (size_t)((k >> 3) & 3) * 1024 + (m & 127) * 8 + (k & 7);
      attnA[dst] = (__bf16)(num[nd][r] / den[r]);
    }
}

extern "C" void kernel_launch(void* const* d_in, const int* in_sizes, int n_in,
                              void* d_out, int out_size, void* d_ws, size_t ws_size,
                              hipStream_t stream) {
  (void)in_sizes; (void)n_in; (void)out_size; (void)ws_size;
  const float* x    = (const float*)d_in[0];
  const float* wqkv = (const float*)d_in[1];
  const float* wout = (const float*)d_in[2];
  float* out = (float*)d_out;
  uint8_t* ws = (uint8_t*)d_ws;

  // workspace layout (bytes); total needed = 96 MB
  __bf16* xbf   = (__bf16*)(ws + 0);                    // 16 MB blocked A (GEMM1)
  __bf16* wqkvt = (__bf16*)(ws + (16ull << 20));        // 24 MB blocked B (GEMM1, RB=48)
  __bf16* woutt = (__bf16*)(ws + (40ull << 20));        //  8 MB blocked B (GEMM2, RB=16)
  __bf16* Qp    = (__bf16*)(ws + (48ull << 20));        // 16 MB [b][h][p][1024][128]
  __bf16* Kp    = (__bf16*)(ws + (64ull << 20));        // 16 MB [b][h][p][1024][128]
  __bf16* Vt    = (__bf16*)(ws + (80ull << 20));        // 16 MB [b][h][p][128][1024]
  __bf16* attnA = (__bf16*)(ws + 0);                    // 16 MB blocked A (GEMM2); reuse xbf

  k_cvt_x_blk<<<4096, 256, 0, stream>>>(x, xbf);
  k_cvt_wt_blk<<<dim3(32, 96), 256, 0, stream>>>(wqkv, wqkvt, 6144, 48);
  k_cvt_wt_blk<<<dim3(32, 32), 256, 0, stream>>>(wout, woutt, 2048, 16);
  // qkv projection: 48 nb, 6 per XCD; grid 1536 = 3 exact rounds at 2/CU
  k_gemm_v8<48, 6, 1><<<1536, 256, 0, stream>>>(xbf, wqkvt, Qp, Kp, Vt, nullptr);
  // fused dilated attention (writes blocked A for GEMM2)
  k_attn<<<1024, 256, 0, stream>>>(Qp, Kp, Vt, attnA);
  // output projection: 16 nb, 2 per XCD; grid 512 = 1 exact round at 2/CU
  k_gemm_v8<16, 2, 2><<<512, 256, 0, stream>>>(attnA, woutt, nullptr, nullptr, nullptr, out);
}